// Round 12
// baseline (384.714 us; speedup 1.0000x reference)
//
#include <hip/hip_runtime.h>
#include <math.h>

// ---- NSA hyperparameters (compile-time, matches reference config) ----
constexpr int kT    = 2048;
constexpr int kHQ   = 16;
constexpr int kD    = 128;
constexpr int kKS   = 32;
constexpr int kST   = 16;
constexpr int kBS   = 64;
constexpr int kM    = (kT - kKS) / kST + 1;   // 127 compressed tokens
constexpr int kNB   = (kT + kBS - 1) / kBS;   // 32 selection blocks
constexpr int kTopN = 16;
constexpr int kNInit = 2;
constexpr int kWIN  = 512;
constexpr float kNEG = -1e30f;
constexpr float kScale = 0.08838834764831845f; // 128^-0.5

constexpr int kPad    = 32;
constexpr int kKBRows = kT + kPad; // 2080
constexpr int kVTCols = kT + kPad; // 2080

constexpr int kQT   = 4;          // queries per block (4 waves)
constexpr int kKstS = 136;        // staged K row stride (bf16 halfwords)
constexpr int kPSt  = 72;         // P row stride (fp16)
constexpr int kPSc  = 132;        // phase A fp32 prob stride
constexpr int kPBc  = 136;        // phase A bf16 prob stride

// union LDS layout (bytes)
constexpr int kKstBytes = 2 * 64 * kKstS * 2;        // 34816 (covers p_s 33792)
constexpr int kPBytes   = 2 * 64 * kPSt * 2;         // 18432 (covers Pb 17408)

typedef __attribute__((ext_vector_type(8))) short short8;
typedef __attribute__((ext_vector_type(8))) _Float16 half8;
typedef __attribute__((ext_vector_type(2))) _Float16 half2v;
typedef __attribute__((ext_vector_type(4))) float floatx4;

// RNE float -> bf16 bits
__device__ inline short f2bf(float x) {
    unsigned u = __float_as_uint(x);
    unsigned r = (u + 0x7fffu + ((u >> 16) & 1u)) >> 16;
    return (short)r;
}

// ---------------------------------------------------------------------
// K1: fused staging.  blocks [0,2080): bf16 K rows + fp16 V^T cols,
// V^T with per-64-block key permutation col = 2l + (kt&1) + 32(kt>>1).
// blocks [2080,2208): mean-pool cmp_k fp32 + cmp V^T bf16.  block=(128)
// ---------------------------------------------------------------------
__global__ void k_stage(const float* __restrict__ k, const float* __restrict__ v,
                        short* __restrict__ kb, _Float16* __restrict__ vt,
                        float* __restrict__ cmp_k, short* __restrict__ cvt) {
    const int bid = blockIdx.x;
    const int d = threadIdx.x;
    if (bid < kKBRows) {
        const int row = bid;
        const int blk = row >> 6, w = row & 63;
        const int kt = w >> 4, l = w & 15;
        const int col = blk * kBS + l * 2 + (kt & 1) + (kt >> 1) * 32;
        if (row < kT) {
            kb[row * kD + d] = f2bf(k[(size_t)row * kD + d]);
            vt[(size_t)d * kVTCols + col] = (_Float16)v[(size_t)row * kD + d];
        } else {
            kb[row * kD + d] = 0;
            vt[(size_t)d * kVTCols + col] = (_Float16)0.f;
        }
    } else {
        const int m = bid - kKBRows;        // 0..127 (127 = zero pad row)
        float sk = 0.f, sv = 0.f;
        if (m < kM) {
            const int base = m * kST;
            #pragma unroll
            for (int i = 0; i < kKS; ++i) {
                sk += k[(size_t)(base + i) * kD + d];
                sv += v[(size_t)(base + i) * kD + d];
            }
            sk *= (1.0f / kKS);
            sv *= (1.0f / kKS);
        }
        cmp_k[m * kD + d] = sk;
        cvt[d * 128 + m] = f2bf(sv);
    }
}

// ---------------------------------------------------------------------
// K2: fully fused NSA kernel.  One block = 4 consecutive t's, 4 waves.
// Phase A (wave-private, no barriers): fp32 cmp QK (bit-identical chains
// to R11), serial per-head softmax (bit-identical), slc_p, serial top-k
// (bit-identical) -> selm_s[wave] in LDS.  Then cmp PV (bf16 MFMA) into
// registers in phase-B dim ownership.  Phase B: R11's staged select+SWA
// flash loop.  Epilogue: out = w0*cmp + w1*sel + w2*swa (single write).
// grid=(T/4), block=(256).
// ---------------------------------------------------------------------
__global__ __launch_bounds__(256, 2) void k_nsa(
        const float* __restrict__ q, const short* __restrict__ kb,
        const _Float16* __restrict__ vt, const float* __restrict__ cmp_k,
        const short* __restrict__ cvt, const float* __restrict__ cw,
        float* __restrict__ out) {
    const int t0 = blockIdx.x * kQT;
    const int tid = threadIdx.x;
    const int wave = tid >> 6;
    const int lane = tid & 63;
    const int l15 = lane & 15;
    const int quad = lane >> 4;
    const int dimw = wave * 32;

    __shared__ __align__(16) char ubuf[kKstBytes + kPBytes];   // 53248 B union
    __shared__ float alphaS[64], alphaW[64], linvS[64], linvW[64];
    __shared__ float sp[kQT][kNB];
    __shared__ unsigned selm_s[kQT];
    __shared__ int blks[33];
    __shared__ int nblk_s;

    // phase A aliases
    float* p_s = (float*)ubuf;                       // [wave][16][kPSc]
    short* Pb  = (short*)(ubuf + kKstBytes);         // [wave][16][kPBc]
    // phase B aliases
    short* Kst0 = (short*)ubuf;
    short* Kst1 = Kst0 + 64 * kKstS;
    _Float16* Psel = (_Float16*)(ubuf + kKstBytes);
    _Float16* Pswa = Psel + 64 * kPSt;

    const int t_w = t0 + wave;

    // ================= PHASE A: compressed attention + top-k =========
    const int nvalid = (t_w >= kKS - 1) ? min(kM, (t_w - (kKS - 1)) / kST + 1) : 0;
    float* ps = p_s + wave * kHQ * kPSc;
    short* pbw = Pb + wave * kHQ * kPBc;
    const float* qg = q + (size_t)t_w * kHQ * kD;

    // QK: fp32, chains bit-identical to R11's k_cmp_attn
    for (int idx = lane; idx < nvalid * 4; idx += 64) {
        const int m = idx >> 2;
        const int h0 = (idx & 3) * 4;
        const float4* k4 = (const float4*)(cmp_k + (size_t)m * kD);
        float a0 = 0.f, a1 = 0.f, a2 = 0.f, a3 = 0.f;
        #pragma unroll 8
        for (int i = 0; i < kD / 4; ++i) {
            const float4 b = k4[i];
            const float4 qa = *(const float4*)(qg + (h0 + 0) * kD + i * 4);
            const float4 qb = *(const float4*)(qg + (h0 + 1) * kD + i * 4);
            const float4 qc = *(const float4*)(qg + (h0 + 2) * kD + i * 4);
            const float4 qd = *(const float4*)(qg + (h0 + 3) * kD + i * 4);
            a0 = fmaf(qa.x, b.x, fmaf(qa.y, b.y, fmaf(qa.z, b.z, fmaf(qa.w, b.w, a0))));
            a1 = fmaf(qb.x, b.x, fmaf(qb.y, b.y, fmaf(qb.z, b.z, fmaf(qb.w, b.w, a1))));
            a2 = fmaf(qc.x, b.x, fmaf(qc.y, b.y, fmaf(qc.z, b.z, fmaf(qc.w, b.w, a2))));
            a3 = fmaf(qd.x, b.x, fmaf(qd.y, b.y, fmaf(qd.z, b.z, fmaf(qd.w, b.w, a3))));
        }
        ps[(h0 + 0) * kPSc + m] = a0 * kScale;
        ps[(h0 + 1) * kPSc + m] = a1 * kScale;
        ps[(h0 + 2) * kPSc + m] = a2 * kScale;
        ps[(h0 + 3) * kPSc + m] = a3 * kScale;
    }

    // serial per-head softmax (bit-identical), lanes 0..15 of each wave
    if (lane < kHQ) {
        float* p = ps + lane * kPSc;
        short* pb = pbw + lane * kPBc;
        if (nvalid == 0) {
            for (int m = 0; m < 128; ++m) { p[m] = 0.f; pb[m] = 0; }
        } else {
            float mx = kNEG;
            for (int m = 0; m < nvalid; ++m) mx = fmaxf(mx, p[m]);
            float l = 0.f;
            for (int m = 0; m < nvalid; ++m) { float e = __expf(p[m] - mx); p[m] = e; l += e; }
            float inv = 1.f / l;
            for (int m = 0; m < nvalid; ++m) { float pn = p[m] * inv; p[m] = pn; pb[m] = f2bf(pn); }
            for (int m = nvalid; m < 128; ++m) { p[m] = 0.f; pb[m] = 0; }
        }
    }

    // slc_p (bit-identical expression), lanes 0..31
    if (lane < kNB) {
        const int b = lane;
        const int m0 = 4 * b;
        float acc = 0.f;
        for (int h = 0; h < kHQ; ++h) {
            const float* p = ps + h * kPSc;
            float a = 0.f;
            a += p[m0];
            a += p[m0 + 1];
            a += p[m0 + 2];
            a += 0.5f * p[m0 + 3];
            if (m0 - 1 >= 0) a += 0.5f * p[m0 - 1];
            acc += a;
        }
        sp[wave][b] = acc;
    }

    // serial top-k (bit-identical), lane 0 of each wave
    if (lane == 0) {
        const int cur = t_w / kBS;
        float vals[kNB];
        #pragma unroll
        for (int b = 0; b < kNB; ++b) {
            float x = sp[wave][b];
            if (b > cur) x = kNEG;
            if (b < kNInit || b == cur) x = 1e30f;
            vals[b] = x;
        }
        unsigned mask = 0;
        for (int n = 0; n < kTopN; ++n) {
            float best = -3.0e38f; int bi = 0;
            #pragma unroll
            for (int b = 0; b < kNB; ++b) {
                bool taken = (mask >> b) & 1u;
                if (!taken && vals[b] > best) { best = vals[b]; bi = b; }
            }
            mask |= (1u << bi);
        }
        selm_s[wave] = mask;
    }
    __syncthreads();   // Pb + selm ready across waves

    const unsigned selm_w = selm_s[wave];
    const unsigned u_union = selm_s[0] | selm_s[1] | selm_s[2] | selm_s[3];
    const int cur_max = (t0 + kQT - 1) >> 6;
    if (tid == 0) {
        int n = 0;
        for (int b = 0; b <= cur_max; ++b) {
            const bool bs = (u_union >> b) & 1u;
            const bool bw = (b * kBS + kBS - 1) >= (t0 - (kWIN - 1));
            if (bs || bw) blks[n++] = b;
        }
        nblk_s = n;
    }

    // cmp PV: bf16 MFMA, accumulate in phase-B dim ownership (regs)
    floatx4 ocmp[kQT][2];
    #pragma unroll
    for (int mt = 0; mt < kQT; ++mt) {
        ocmp[mt][0] = (floatx4){0,0,0,0};
        ocmp[mt][1] = (floatx4){0,0,0,0};
        #pragma unroll
        for (int kc = 0; kc < 4; ++kc) {
            const short8 ap = *(const short8*)&Pb[(mt * kHQ + l15) * kPBc + kc * 32 + quad * 8];
            #pragma unroll
            for (int nt = 0; nt < 2; ++nt) {
                const short8 b = *(const short8*)(cvt + (size_t)(dimw + nt * 16 + l15) * 128 + kc * 32 + quad * 8);
                ocmp[mt][nt] = __builtin_amdgcn_mfma_f32_16x16x32_bf16(ap, b, ocmp[mt][nt], 0, 0, 0);
            }
        }
    }
    __syncthreads();   // Pb reads done; blks ready -> safe to overwrite union

    // ================= PHASE B: select + SWA flash loop ==============
    const int nblk = nblk_s;

    // A-fragments: q * kScale -> bf16
    short8 aq[4];
    {
        const float* qp = q + ((size_t)t_w * kHQ + l15) * kD + quad * 8;
        #pragma unroll
        for (int c = 0; c < 4; ++c) {
            const float4 f0 = *(const float4*)(qp + c * 32);
            const float4 f1 = *(const float4*)(qp + c * 32 + 4);
            short8 a;
            a[0] = f2bf(f0.x * kScale); a[1] = f2bf(f0.y * kScale);
            a[2] = f2bf(f0.z * kScale); a[3] = f2bf(f0.w * kScale);
            a[4] = f2bf(f1.x * kScale); a[5] = f2bf(f1.y * kScale);
            a[6] = f2bf(f1.z * kScale); a[7] = f2bf(f1.w * kScale);
            aq[c] = a;
        }
    }

    // prestage blks[0] into Kst0
    {
        const int b0 = blks[0];
        const int row = tid >> 2, seg = tid & 3;
        const short* src = kb + (size_t)(b0 * kBS + row) * kD + seg * 32;
        short* dst = Kst0 + row * kKstS + seg * 32;
        #pragma unroll
        for (int i = 0; i < 4; ++i)
            *(short8*)(dst + i * 8) = *(const short8*)(src + i * 8);
    }

    float msel[4], lsel[4], mswa[4], lswa[4];
    #pragma unroll
    for (int r = 0; r < 4; ++r) { msel[r] = kNEG; lsel[r] = 0.f; mswa[r] = kNEG; lswa[r] = 0.f; }
    floatx4 osel[kQT][2], oswa[kQT][2];
    #pragma unroll
    for (int mt = 0; mt < kQT; ++mt)
        #pragma unroll
        for (int nt = 0; nt < 2; ++nt) {
            osel[mt][nt] = (floatx4){0,0,0,0};
            oswa[mt][nt] = (floatx4){0,0,0,0};
        }

    __syncthreads();   // prestage visible

    for (int i = 0; i < nblk; ++i) {
        const int b = blks[i];
        short* KstC = (i & 1) ? Kst1 : Kst0;
        short* KstN = (i & 1) ? Kst0 : Kst1;
        const bool bsel = (u_union >> b) & 1u;
        const bool bswa = (b * kBS + kBS - 1) >= (t0 - (kWIN - 1));

        // early global loads: V frags (this block) + next K rows
        half8 vf[2][2];
        #pragma unroll
        for (int nt = 0; nt < 2; ++nt)
            #pragma unroll
            for (int kc = 0; kc < 2; ++kc)
                vf[nt][kc] = *(const half8*)(vt + (size_t)(dimw + nt * 16 + l15) * kVTCols
                                             + b * kBS + kc * 32 + quad * 8);
        short8 kreg[4];
        {
            const int nb_ = (i + 1 < nblk) ? blks[i + 1] : b;
            const int row = tid >> 2, seg = tid & 3;
            const short* src = kb + (size_t)(nb_ * kBS + row) * kD + seg * 32;
            #pragma unroll
            for (int j = 0; j < 4; ++j)
                kreg[j] = *(const short8*)(src + j * 8);
        }

        // QK from staged K (scores pre-scaled)
        floatx4 acc[4];
        #pragma unroll
        for (int kt = 0; kt < 4; ++kt) {
            acc[kt] = (floatx4){0,0,0,0};
            #pragma unroll
            for (int c = 0; c < 4; ++c) {
                const short8 bf = *(const short8*)&KstC[(kt * 16 + l15) * kKstS + c * 32 + quad * 8];
                acc[kt] = __builtin_amdgcn_mfma_f32_16x16x32_bf16(aq[c], bf, acc[kt], 0, 0, 0);
            }
        }

        const bool mem = (selm_w >> b) & 1u;
        bool ca[4], wi[4];
        #pragma unroll
        for (int kt = 0; kt < 4; ++kt) {
            const int key = b * kBS + kt * 16 + l15;
            ca[kt] = key <= t_w;
            wi[kt] = ca[kt] && (t_w - key) < kWIN;
        }

        // online softmax (shared-exp between sel and swa)
        float axs[4], axw[4];
        #pragma unroll
        for (int r = 0; r < 4; ++r) {
            float mxs = kNEG, mxw = kNEG;
            #pragma unroll
            for (int kt = 0; kt < 4; ++kt) {
                const float s = acc[kt][r];
                if (mem && ca[kt]) mxs = fmaxf(mxs, s);
                if (wi[kt]) mxw = fmaxf(mxw, s);
            }
            #pragma unroll
            for (int off = 8; off; off >>= 1) {
                mxs = fmaxf(mxs, __shfl_xor(mxs, off, 16));
                mxw = fmaxf(mxw, __shfl_xor(mxw, off, 16));
            }
            const float msn = fmaxf(msel[r], mxs);
            const float mwn = fmaxf(mswa[r], mxw);
            axs[r] = __expf(msel[r] - msn);
            axw[r] = __expf(mswa[r] - mwn);

            float es[4], ew[4];
            if (mem) {
                const float cr = __expf(msn - mwn);
                #pragma unroll
                for (int kt = 0; kt < 4; ++kt) {
                    const float e0 = ca[kt] ? __expf(acc[kt][r] - msn) : 0.f;
                    es[kt] = e0;
                    ew[kt] = wi[kt] ? e0 * cr : 0.f;
                }
            } else {
                #pragma unroll
                for (int kt = 0; kt < 4; ++kt) {
                    es[kt] = 0.f;
                    ew[kt] = wi[kt] ? __expf(acc[kt][r] - mwn) : 0.f;
                }
            }
            float sums = (es[0] + es[1]) + (es[2] + es[3]);
            float sumw = (ew[0] + ew[1]) + (ew[2] + ew[3]);
            #pragma unroll
            for (int off = 8; off; off >>= 1) {
                sums += __shfl_xor(sums, off, 16);
                sumw += __shfl_xor(sumw, off, 16);
            }
            lsel[r] = lsel[r] * axs[r] + sums; msel[r] = msn;
            lswa[r] = lswa[r] * axw[r] + sumw; mswa[r] = mwn;

            // packed P writes (perm col = 2*l15 + (kt&1) + 32*(kt>>1))
            const int prow = (wave * 16 + quad * 4 + r) * kPSt;
            if (bsel) {
                *(half2v*)&Psel[prow + 2 * l15]      = (half2v){(_Float16)es[0], (_Float16)es[1]};
                *(half2v*)&Psel[prow + 32 + 2 * l15] = (half2v){(_Float16)es[2], (_Float16)es[3]};
            }
            if (bswa) {
                *(half2v*)&Pswa[prow + 2 * l15]      = (half2v){(_Float16)ew[0], (_Float16)ew[1]};
                *(half2v*)&Pswa[prow + 32 + 2 * l15] = (half2v){(_Float16)ew[2], (_Float16)ew[3]};
            }
        }
        if (l15 == 0) {
            *(float4*)&alphaS[wave * 16 + quad * 4] = make_float4(axs[0], axs[1], axs[2], axs[3]);
            *(float4*)&alphaW[wave * 16 + quad * 4] = make_float4(axw[0], axw[1], axw[2], axw[3]);
        }
        __syncthreads();   // P + alpha ready

        // PV: wave owns dims [32w,32w+32)
        if (bsel) {
            #pragma unroll
            for (int mt = 0; mt < kQT; ++mt) {
                const float4 a4 = *(const float4*)&alphaS[mt * 16 + quad * 4];
                const float av[4] = {a4.x, a4.y, a4.z, a4.w};
                #pragma unroll
                for (int nt = 0; nt < 2; ++nt)
                    #pragma unroll
                    for (int r = 0; r < 4; ++r) osel[mt][nt][r] *= av[r];
                #pragma unroll
                for (int kc = 0; kc < 2; ++kc) {
                    const half8 ap = *(const half8*)&Psel[(mt * 16 + l15) * kPSt + kc * 32 + quad * 8];
                    #pragma unroll
                    for (int nt = 0; nt < 2; ++nt)
                        osel[mt][nt] = __builtin_amdgcn_mfma_f32_16x16x32_f16(ap, vf[nt][kc], osel[mt][nt], 0, 0, 0);
                }
            }
        }
        if (bswa) {
            #pragma unroll
            for (int mt = 0; mt < kQT; ++mt) {
                const float4 a4 = *(const float4*)&alphaW[mt * 16 + quad * 4];
                const float av[4] = {a4.x, a4.y, a4.z, a4.w};
                #pragma unroll
                for (int nt = 0; nt < 2; ++nt)
                    #pragma unroll
                    for (int r = 0; r < 4; ++r) oswa[mt][nt][r] *= av[r];
                #pragma unroll
                for (int kc = 0; kc < 2; ++kc) {
                    const half8 ap = *(const half8*)&Pswa[(mt * 16 + l15) * kPSt + kc * 32 + quad * 8];
                    #pragma unroll
                    for (int nt = 0; nt < 2; ++nt)
                        oswa[mt][nt] = __builtin_amdgcn_mfma_f32_16x16x32_f16(ap, vf[nt][kc], oswa[mt][nt], 0, 0, 0);
                }
            }
        }

        // stage next block into the other Kst buffer
        if (i + 1 < nblk) {
            const int row = tid >> 2, seg = tid & 3;
            short* dst = KstN + row * kKstS + seg * 32;
            #pragma unroll
            for (int j = 0; j < 4; ++j)
                *(short8*)(dst + j * 8) = kreg[j];
        }
        __syncthreads();   // next Kst visible; P reads done
    }

    // ================= epilogue: combine all three branches ==========
    if (l15 == 0) {
        *(float4*)&linvS[wave * 16 + quad * 4] =
            make_float4(1.f / lsel[0], 1.f / lsel[1], 1.f / lsel[2], 1.f / lsel[3]);
        *(float4*)&linvW[wave * 16 + quad * 4] =
            make_float4(1.f / lswa[0], 1.f / lswa[1], 1.f / lswa[2], 1.f / lswa[3]);
    }
    __syncthreads();

    #pragma unroll
    for (int mt = 0; mt < kQT; ++mt) {
        const int tt = t0 + mt;
        #pragma unroll
        for (int r = 0; r < 4; ++r) {
            const int h = quad * 4 + r;
            const float ls = linvS[mt * 16 + h];
            const float lw = linvW[mt * 16 + h];
            const float c0 = cw[((size_t)tt * kHQ + h) * 3 + 0];
            const float c1 = cw[((size_t)tt * kHQ + h) * 3 + 1];
            const float c2 = cw[((size_t)tt * kHQ + h) * 3 + 2];
            const float w0 = 1.f / (1.f + __expf(-c0));
            const float w1 = 1.f / (1.f + __expf(-c1));
            const float w2 = 1.f / (1.f + __expf(-c2));
            #pragma unroll
            for (int nt = 0; nt < 2; ++nt) {
                const int dim = dimw + nt * 16 + l15;
                out[((size_t)tt * kHQ + h) * kD + dim] =
                    w0 * ocmp[mt][nt][r] + w1 * osel[mt][nt][r] * ls + w2 * oswa[mt][nt][r] * lw;
            }
        }
    }
}

// ---------------------------------------------------------------------
extern "C" void kernel_launch(void* const* d_in, const int* in_sizes, int n_in,
                              void* d_out, int out_size, void* d_ws, size_t ws_size,
                              hipStream_t stream) {
    const float* q  = (const float*)d_in[0];
    const float* k  = (const float*)d_in[1];
    const float* v  = (const float*)d_in[2];
    const float* cw = (const float*)d_in[3];
    float* out = (float*)d_out;

    float* ws = (float*)d_ws;
    float* cmp_k = ws;                                        // 128*128 fp32
    short* kb      = (short*)(cmp_k + 128 * kD);              // kKBRows*kD bf16
    _Float16* vt   = (_Float16*)(kb + (size_t)kKBRows * kD);  // kD*kVTCols fp16
    short* cvt     = (short*)(vt + (size_t)kD * kVTCols);     // 128*128 bf16

    k_stage<<<dim3(kKBRows + 128), dim3(kD), 0, stream>>>(k, v, kb, vt, cmp_k, cvt);
    k_nsa<<<dim3(kT / kQT), dim3(256), 0, stream>>>(q, kb, vt, cmp_k, cvt, cw, out);
}